// Round 4
// baseline (1089.193 us; speedup 1.0000x reference)
//
#include <hip/hip_runtime.h>

typedef _Float16 f16x8 __attribute__((ext_vector_type(8)));
typedef _Float16 f16x4 __attribute__((ext_vector_type(4)));
typedef float    f32x4 __attribute__((ext_vector_type(4)));

#define MFMA16(a, b, c) __builtin_amdgcn_mfma_f32_16x16x32_f16((a), (b), (c), 0, 0, 0)

// ---------- fragment helpers ----------
// Universal row-chunk load: lane reads 16B at [row = r0 + (lane&15)][col = c0 + 8*(lane>>4) .. +7]
// Interpreted as A: A[i][k] = M[i][k].  Interpreted as B: B[k][n] = M[n][k].
__device__ __forceinline__ f16x8 ldsFrag512(const _Float16* base, int r0, int c0, int lane) {
    int row = r0 + (lane & 15);
    int off = ((c0 + ((lane >> 4) << 3)) << 1) ^ ((row & 7) << 4);
    return *reinterpret_cast<const f16x8*>(reinterpret_cast<const char*>(base) + row * 512 + off);
}
__device__ __forceinline__ f16x8 ldsFrag128(const _Float16* base, int r0, int c0, int lane) {
    int row = r0 + (lane & 15);
    int off = ((c0 + ((lane >> 4) << 3)) << 1) ^ ((row & 7) << 4);
    return *reinterpret_cast<const f16x8*>(reinterpret_cast<const char*>(base) + row * 128 + off);
}
// Global weight frag (row-major [256][256] f16, L2-resident, no swizzle)
__device__ __forceinline__ f16x8 gFrag(const _Float16* __restrict__ W, int r0, int c0, int lane) {
    return *reinterpret_cast<const f16x8*>(W + (r0 + (lane & 15)) * 256 + c0 + ((lane >> 4) << 3));
}
// Store D-frag transposed: the 4 acc values (D rows orow_dim = ocol0..ocol0+3 at fixed D col = orow)
// land as 4 consecutive f16 in row `orow` of a row-major swizzled buffer. 8B store.
__device__ __forceinline__ void stDT128(_Float16* base, int orow, int ocol0, f32x4 v) {
    f16x4 p = { (_Float16)v[0], (_Float16)v[1], (_Float16)v[2], (_Float16)v[3] };
    int off = (ocol0 << 1) ^ ((orow & 7) << 4);
    *reinterpret_cast<f16x4*>(reinterpret_cast<char*>(base) + orow * 128 + off) = p;
}
__device__ __forceinline__ void stDT512(_Float16* base, int orow, int ocol0, f32x4 v) {
    f16x4 p = { (_Float16)v[0], (_Float16)v[1], (_Float16)v[2], (_Float16)v[3] };
    int off = (ocol0 << 1) ^ ((orow & 7) << 4);
    *reinterpret_cast<f16x4*>(reinterpret_cast<char*>(base) + orow * 512 + off) = p;
}

// ---------- pre-kernel: weights fp32 -> fp16, bias gather into per-lane frag layout ----------
__global__ void prep_kernel(const float* __restrict__ Wq, const float* __restrict__ Wk,
                            const float* __restrict__ Wv, const float* __restrict__ Wo,
                            const float* __restrict__ table, const int* __restrict__ rel,
                            _Float16* __restrict__ wq, _Float16* __restrict__ wk,
                            _Float16* __restrict__ wv, _Float16* __restrict__ wo,
                            f32x4* __restrict__ biasP) {
    int t = blockIdx.x * 256 + threadIdx.x;   // 65536 threads
    wq[t] = (_Float16)Wq[t];
    wk[t] = (_Float16)Wk[t];
    wv[t] = (_Float16)Wv[t];
    wo[t] = (_Float16)Wo[t];
    if (t < 8192) {
        // biasP[((gh*4 + mt)*4 + lt)*64 + lane] = {val(r=0..3)};  val = bias[gh][l][m]
        int lane = t & 63, lt = (t >> 6) & 3, mt = (t >> 8) & 3, gh = t >> 10;
        int l = 16 * lt + (lane & 15);
        f32x4 v;
#pragma unroll
        for (int r = 0; r < 4; ++r) {
            int m = 16 * mt + 4 * (lane >> 4) + r;
            v[r] = table[gh * 225 + rel[l * 64 + m]];
        }
        biasP[t] = v;
    }
}

// ---------- q/k projection, transposed compute: D[ch][tok] = W_slice @ xw^T ----------
__device__ __forceinline__ void gemm_qk(const _Float16* __restrict__ Wg, const _Float16* xw,
                                        _Float16* scr, int w, int lane) {
    f32x4 z = {0.f, 0.f, 0.f, 0.f};
    f32x4 acc[4][4];
#pragma unroll
    for (int i = 0; i < 4; ++i)
#pragma unroll
        for (int j = 0; j < 4; ++j) acc[i][j] = z;
    for (int ks = 0; ks < 8; ++ks) {
        f16x8 A[4], B[4];
#pragma unroll
        for (int rt = 0; rt < 4; ++rt) A[rt] = gFrag(Wg, 64 * w + 16 * rt, 32 * ks, lane);
#pragma unroll
        for (int ct = 0; ct < 4; ++ct) B[ct] = ldsFrag512(xw, 16 * ct, 32 * ks, lane);
#pragma unroll
        for (int rt = 0; rt < 4; ++rt)
#pragma unroll
            for (int ct = 0; ct < 4; ++ct) acc[rt][ct] = MFMA16(A[rt], B[ct], acc[rt][ct]);
    }
    int cl = lane & 15, g4 = (lane >> 4) << 2;
#pragma unroll
    for (int rt = 0; rt < 4; ++rt)
#pragma unroll
        for (int ct = 0; ct < 4; ++ct)   // scratch becomes [tok][ch64] row-major
            stDT128(scr, 16 * ct + cl, 16 * rt + g4, acc[rt][ct]);
}

// ---------- v projection, normal compute: D[tok][ch]; stored transposed -> vT [ch64][tok] ----------
__device__ __forceinline__ void gemm_v(const _Float16* __restrict__ Wg, const _Float16* xw,
                                       _Float16* scr, int w, int lane) {
    f32x4 z = {0.f, 0.f, 0.f, 0.f};
    f32x4 acc[4][4];
#pragma unroll
    for (int i = 0; i < 4; ++i)
#pragma unroll
        for (int j = 0; j < 4; ++j) acc[i][j] = z;
    for (int ks = 0; ks < 8; ++ks) {
        f16x8 A[4], B[4];
#pragma unroll
        for (int rt = 0; rt < 4; ++rt) A[rt] = ldsFrag512(xw, 16 * rt, 32 * ks, lane);
#pragma unroll
        for (int ct = 0; ct < 4; ++ct) B[ct] = gFrag(Wg, 64 * w + 16 * ct, 32 * ks, lane);
#pragma unroll
        for (int rt = 0; rt < 4; ++rt)
#pragma unroll
            for (int ct = 0; ct < 4; ++ct) acc[rt][ct] = MFMA16(A[rt], B[ct], acc[rt][ct]);
    }
    int cl = lane & 15, g4 = (lane >> 4) << 2;
#pragma unroll
    for (int rt = 0; rt < 4; ++rt)
#pragma unroll
        for (int ct = 0; ct < 4; ++ct)   // orow = ch64, ocol = tok  -> vT layout
            stDT128(scr, 16 * ct + cl, 16 * rt + g4, acc[rt][ct]);
}

// ---------- main fused kernel: 1 window per block, 4 waves, 2 heads/wave ----------
__global__ __launch_bounds__(256, 2)
void winattn_main(const float* __restrict__ x,
                  const _Float16* __restrict__ Wq, const _Float16* __restrict__ Wk,
                  const _Float16* __restrict__ Wv, const _Float16* __restrict__ Wo,
                  const f32x4* __restrict__ biasP, const float* __restrict__ bo,
                  float* __restrict__ out) {
    __shared__ __align__(16) _Float16 sm_a[64 * 256];      // xw, later o   (32 KB)
    __shared__ __align__(16) _Float16 sm_scr[4][64 * 64];  // per-wave scratch (32 KB)

    const int tid = threadIdx.x;
    const int lane = tid & 63;
    const int w = tid >> 6;
    const int g = lane >> 4;
    const int cl = lane & 15;
    const int bid = blockIdx.x;
    const int bb = bid >> 10, wy = (bid >> 5) & 31, wx = bid & 31;
    const float* xb = x + (size_t)bb * 16777216u;          // 256*65536 floats per batch
    const int sp = wy * 8 * 256 + wx * 8;                  // spatial base within one channel plane

    // ---- Stage 1: x window -> LDS xw [64 tok][256 ch] f16, swizzled ----
    for (int i = 0; i < 16; ++i) {
        int qi = tid + (i << 8);                 // 4096 float4 chunks
        int c = qi >> 4;
        int iy = (qi >> 1) & 7, ixh = qi & 1;
        f32x4 v4 = *reinterpret_cast<const f32x4*>(xb + (size_t)c * 65536 + sp + iy * 256 + ixh * 4);
        int l0 = iy * 8 + ixh * 4;
#pragma unroll
        for (int r = 0; r < 4; ++r) {
            int l = l0 + r;
            *reinterpret_cast<_Float16*>(reinterpret_cast<char*>(sm_a) + l * 512 +
                                         ((c << 1) ^ ((l & 7) << 4))) = (_Float16)v4[r];
        }
    }
    __syncthreads();

    _Float16* scr = sm_scr[w];
    f16x8 qf[2][4], kf[2][4], vf[2][4];

    // ---- q^T, k^T, v -> register fragments (scratch reused sequentially; compiler orders via LDS aliasing) ----
    gemm_qk(Wq, sm_a, scr, w, lane);
#pragma unroll
    for (int h = 0; h < 2; ++h)
#pragma unroll
        for (int lt = 0; lt < 4; ++lt) qf[h][lt] = ldsFrag128(scr, 16 * lt, 32 * h, lane);

    gemm_qk(Wk, sm_a, scr, w, lane);
#pragma unroll
    for (int h = 0; h < 2; ++h)
#pragma unroll
        for (int mt = 0; mt < 4; ++mt) kf[h][mt] = ldsFrag128(scr, 16 * mt, 32 * h, lane);

    gemm_v(Wv, sm_a, scr, w, lane);
#pragma unroll
    for (int h = 0; h < 2; ++h)
#pragma unroll
        for (int vt = 0; vt < 2; ++vt)
#pragma unroll
            for (int kb = 0; kb < 2; ++kb)
                vf[h][2 * vt + kb] = ldsFrag128(scr, 32 * h + 16 * vt, 32 * kb, lane);

    __syncthreads();   // all waves done with xw; sm_a becomes the o buffer

    // ---- attention per head: S^T = K @ Q^T, softmax over rows(m), o^T = V^T @ P^T ----
#pragma unroll
    for (int h = 0; h < 2; ++h) {
        int gh = 2 * w + h;
        f32x4 t[4][4];
#pragma unroll
        for (int mt = 0; mt < 4; ++mt)
#pragma unroll
            for (int lt = 0; lt < 4; ++lt) {
                f32x4 s = {0.f, 0.f, 0.f, 0.f};
                s = MFMA16(kf[h][mt], qf[h][lt], s);
                t[mt][lt] = s * 0.17677669529663687f + biasP[(gh * 16 + mt * 4 + lt) * 64 + lane];
            }
        // softmax over m = (mt, r) for each column l (= lt, lane&15)
#pragma unroll
        for (int lt = 0; lt < 4; ++lt) {
            float mx = -1e30f;
#pragma unroll
            for (int mt = 0; mt < 4; ++mt)
#pragma unroll
                for (int r = 0; r < 4; ++r) mx = fmaxf(mx, t[mt][lt][r]);
            mx = fmaxf(mx, __shfl_xor(mx, 16));
            mx = fmaxf(mx, __shfl_xor(mx, 32));
            float sum = 0.f;
#pragma unroll
            for (int mt = 0; mt < 4; ++mt)
#pragma unroll
                for (int r = 0; r < 4; ++r) {
                    float e = exp2f((t[mt][lt][r] - mx) * 1.4426950408889634f);
                    t[mt][lt][r] = e;
                    sum += e;
                }
            sum += __shfl_xor(sum, 16);
            sum += __shfl_xor(sum, 32);
            float rs = 1.0f / sum;
#pragma unroll
            for (int mt = 0; mt < 4; ++mt)
#pragma unroll
                for (int r = 0; r < 4; ++r) t[mt][lt][r] *= rs;
        }
        // store P as row-major [l][m] (contiguous 8B stores)
#pragma unroll
        for (int mt = 0; mt < 4; ++mt)
#pragma unroll
            for (int lt = 0; lt < 4; ++lt)
                stDT128(scr, 16 * lt + cl, 16 * mt + ((lane >> 4) << 2), t[mt][lt]);
        // PV: o^T = V^T @ P^T
        f32x4 oacc[2][4];
        {
            f32x4 z = {0.f, 0.f, 0.f, 0.f};
#pragma unroll
            for (int vt = 0; vt < 2; ++vt)
#pragma unroll
                for (int lt = 0; lt < 4; ++lt) oacc[vt][lt] = z;
        }
#pragma unroll
        for (int lt = 0; lt < 4; ++lt)
#pragma unroll
            for (int kb = 0; kb < 2; ++kb) {
                f16x8 pf = ldsFrag128(scr, 16 * lt, 32 * kb, lane);
#pragma unroll
                for (int vt = 0; vt < 2; ++vt)
                    oacc[vt][lt] = MFMA16(vf[h][2 * vt + kb], pf, oacc[vt][lt]);
            }
        // o -> sm_a [tok][256 ch]
#pragma unroll
        for (int vt = 0; vt < 2; ++vt)
#pragma unroll
            for (int lt = 0; lt < 4; ++lt)
                stDT512(sm_a, 16 * lt + cl, 64 * w + 32 * h + 16 * vt + ((lane >> 4) << 2),
                        oacc[vt][lt]);
    }
    __syncthreads();

    // ---- output projection: out[tok][oc] = o @ Wo^T + bo, direct float4 global stores ----
    {
        f32x4 z = {0.f, 0.f, 0.f, 0.f};
        f32x4 acc[4][4];
#pragma unroll
        for (int i = 0; i < 4; ++i)
#pragma unroll
            for (int j = 0; j < 4; ++j) acc[i][j] = z;
        for (int ks = 0; ks < 8; ++ks) {
            f16x8 A[4], B[4];
#pragma unroll
            for (int rt = 0; rt < 4; ++rt) A[rt] = ldsFrag512(sm_a, 16 * rt, 32 * ks, lane);
#pragma unroll
            for (int ct = 0; ct < 4; ++ct) B[ct] = gFrag(Wo, 64 * w + 16 * ct, 32 * ks, lane);
#pragma unroll
            for (int rt = 0; rt < 4; ++rt)
#pragma unroll
                for (int ct = 0; ct < 4; ++ct) acc[rt][ct] = MFMA16(A[rt], B[ct], acc[rt][ct]);
        }
#pragma unroll
        for (int ct = 0; ct < 4; ++ct) {
            int oc = 64 * w + 16 * ct + cl;
            float bov = bo[oc];
            size_t obase = ((size_t)(bb * 256 + oc)) * 65536u + sp;
#pragma unroll
            for (int rt = 0; rt < 4; ++rt) {
                int l0 = 16 * rt + 4 * g;        // 4 consecutive tokens -> 4 consecutive ww
                int iy = l0 >> 3, ix0 = l0 & 7;
                f32x4 vst = acc[rt][ct] + bov;
                *reinterpret_cast<f32x4*>(out + obase + iy * 256 + ix0) = vst;
            }
        }
    }
}

extern "C" void kernel_launch(void* const* d_in, const int* in_sizes, int n_in,
                              void* d_out, int out_size, void* d_ws, size_t ws_size,
                              hipStream_t stream) {
    (void)in_sizes; (void)n_in; (void)out_size; (void)ws_size;
    const float* x     = (const float*)d_in[0];
    const float* Wq    = (const float*)d_in[1];
    const float* Wk    = (const float*)d_in[2];
    const float* Wv    = (const float*)d_in[3];
    const float* table = (const float*)d_in[4];
    const float* Wo    = (const float*)d_in[5];
    const float* bo    = (const float*)d_in[6];
    const int*   rel   = (const int*)d_in[7];

    char* ws = (char*)d_ws;
    _Float16* wq = (_Float16*)(ws + 0);
    _Float16* wk = (_Float16*)(ws + 131072);
    _Float16* wv = (_Float16*)(ws + 262144);
    _Float16* wo = (_Float16*)(ws + 393216);
    f32x4*    bp = (f32x4*)(ws + 524288);     // 8192 float4 = 128 KB

    prep_kernel<<<256, 256, 0, stream>>>(Wq, Wk, Wv, Wo, table, rel, wq, wk, wv, wo, bp);
    winattn_main<<<4096, 256, 0, stream>>>(x, wq, wk, wv, wo, bp, bo, (float*)d_out);
}

// Round 11
// 753.490 us; speedup vs baseline: 1.4455x; 1.4455x over previous
//
#include <hip/hip_runtime.h>

typedef _Float16 f16x8 __attribute__((ext_vector_type(8)));
typedef _Float16 f16x4 __attribute__((ext_vector_type(4)));
typedef float    f32x4 __attribute__((ext_vector_type(4)));

#define MFMA16(a, b, c) __builtin_amdgcn_mfma_f32_16x16x32_f16((a), (b), (c), 0, 0, 0)

// row-dependent XOR swizzle: spreads banks for both strided writes and tile reads
__device__ __forceinline__ int swzb(int row) { return ((row ^ (row >> 3)) & 7) << 4; }

// ---------- fragment helpers ----------
// lane reads 16B at [row = r0 + (lane&15)][col = c0 + 8*(lane>>4) .. +7]
// As A: A[i][k] = M[i][k].  As B: B[k][n] = M[n][k].
__device__ __forceinline__ f16x8 ldsFrag512(const _Float16* base, int r0, int c0, int lane) {
    int row = r0 + (lane & 15);
    int off = ((c0 + ((lane >> 4) << 3)) << 1) ^ swzb(row);
    return *reinterpret_cast<const f16x8*>(reinterpret_cast<const char*>(base) + row * 512 + off);
}
__device__ __forceinline__ f16x8 ldsFrag128(const _Float16* base, int r0, int c0, int lane) {
    int row = r0 + (lane & 15);
    int off = ((c0 + ((lane >> 4) << 3)) << 1) ^ swzb(row);
    return *reinterpret_cast<const f16x8*>(reinterpret_cast<const char*>(base) + row * 128 + off);
}
// Global weight frag (row-major [256][256] f16, L2-resident)
__device__ __forceinline__ f16x8 gFrag(const _Float16* __restrict__ W, int r0, int c0, int lane) {
    return *reinterpret_cast<const f16x8*>(W + (r0 + (lane & 15)) * 256 + c0 + ((lane >> 4) << 3));
}
// Store D-frag transposed: 4 acc values -> 4 consecutive f16 in row `orow`. 8B store.
__device__ __forceinline__ void stDT128(_Float16* base, int orow, int ocol0, f32x4 v) {
    f16x4 p = { (_Float16)v[0], (_Float16)v[1], (_Float16)v[2], (_Float16)v[3] };
    int off = (ocol0 << 1) ^ swzb(orow);
    *reinterpret_cast<f16x4*>(reinterpret_cast<char*>(base) + orow * 128 + off) = p;
}
__device__ __forceinline__ void stDT512(_Float16* base, int orow, int ocol0, f32x4 v) {
    f16x4 p = { (_Float16)v[0], (_Float16)v[1], (_Float16)v[2], (_Float16)v[3] };
    int off = (ocol0 << 1) ^ swzb(orow);
    *reinterpret_cast<f16x4*>(reinterpret_cast<char*>(base) + orow * 512 + off) = p;
}

// ---------- pre-kernel: weights fp32 -> fp16, bias gather into per-lane frag layout ----------
__global__ void prep_kernel(const float* __restrict__ Wq, const float* __restrict__ Wk,
                            const float* __restrict__ Wv, const float* __restrict__ Wo,
                            const float* __restrict__ table, const int* __restrict__ rel,
                            _Float16* __restrict__ wq, _Float16* __restrict__ wk,
                            _Float16* __restrict__ wv, _Float16* __restrict__ wo,
                            f32x4* __restrict__ biasP) {
    int t = blockIdx.x * 256 + threadIdx.x;   // 65536 threads
    wq[t] = (_Float16)Wq[t];
    wk[t] = (_Float16)Wk[t];
    wv[t] = (_Float16)Wv[t];
    wo[t] = (_Float16)Wo[t];
    if (t < 8192) {
        // biasP[((gh*4 + mt)*4 + lt)*64 + lane] = {val(r=0..3)};  val = bias[gh][l][m]
        int lane = t & 63, lt = (t >> 6) & 3, mt = (t >> 8) & 3, gh = t >> 10;
        int l = 16 * lt + (lane & 15);
        f32x4 v;
#pragma unroll
        for (int r = 0; r < 4; ++r) {
            int m = 16 * mt + 4 * (lane >> 4) + r;
            v[r] = table[gh * 225 + rel[l * 64 + m]];
        }
        biasP[t] = v;
    }
}

// ---------- q/k projection, transposed compute: D[ch][tok] = W_slice @ xw^T ----------
// xw rows offset by tb (window token base). scr becomes [tok][ch64] row-major.
__device__ __forceinline__ void gemm_qk(const _Float16* __restrict__ Wg, const _Float16* xw,
                                        _Float16* scr, int cslice, int tb, int lane) {
    f32x4 z = {0.f, 0.f, 0.f, 0.f};
    f32x4 acc[4][4];
#pragma unroll
    for (int i = 0; i < 4; ++i)
#pragma unroll
        for (int j = 0; j < 4; ++j) acc[i][j] = z;
    for (int ks = 0; ks < 8; ++ks) {
        f16x8 A[4], B[4];
#pragma unroll
        for (int rt = 0; rt < 4; ++rt) A[rt] = gFrag(Wg, 64 * cslice + 16 * rt, 32 * ks, lane);
#pragma unroll
        for (int ct = 0; ct < 4; ++ct) B[ct] = ldsFrag512(xw, tb + 16 * ct, 32 * ks, lane);
#pragma unroll
        for (int rt = 0; rt < 4; ++rt)
#pragma unroll
            for (int ct = 0; ct < 4; ++ct) acc[rt][ct] = MFMA16(A[rt], B[ct], acc[rt][ct]);
    }
    int cl = lane & 15, g4 = (lane >> 4) << 2;
#pragma unroll
    for (int rt = 0; rt < 4; ++rt)
#pragma unroll
        for (int ct = 0; ct < 4; ++ct)
            stDT128(scr, 16 * ct + cl, 16 * rt + g4, acc[rt][ct]);
}

// ---------- v projection, normal compute: D[tok][ch]; stored transposed -> vT [ch64][tok] ----------
__device__ __forceinline__ void gemm_v(const _Float16* __restrict__ Wg, const _Float16* xw,
                                       _Float16* scr, int cslice, int tb, int lane) {
    f32x4 z = {0.f, 0.f, 0.f, 0.f};
    f32x4 acc[4][4];
#pragma unroll
    for (int i = 0; i < 4; ++i)
#pragma unroll
        for (int j = 0; j < 4; ++j) acc[i][j] = z;
    for (int ks = 0; ks < 8; ++ks) {
        f16x8 A[4], B[4];
#pragma unroll
        for (int rt = 0; rt < 4; ++rt) A[rt] = ldsFrag512(xw, tb + 16 * rt, 32 * ks, lane);
#pragma unroll
        for (int ct = 0; ct < 4; ++ct) B[ct] = gFrag(Wg, 64 * cslice + 16 * ct, 32 * ks, lane);
#pragma unroll
        for (int rt = 0; rt < 4; ++rt)
#pragma unroll
            for (int ct = 0; ct < 4; ++ct) acc[rt][ct] = MFMA16(A[rt], B[ct], acc[rt][ct]);
    }
    int cl = lane & 15, g4 = (lane >> 4) << 2;
#pragma unroll
    for (int rt = 0; rt < 4; ++rt)
#pragma unroll
        for (int ct = 0; ct < 4; ++ct)
            stDT128(scr, 16 * ct + cl, 16 * rt + g4, acc[rt][ct]);
}

// ---------- main fused kernel: 2 adjacent windows per block, 8 waves ----------
// waves 0-3 -> window 0 (heads 2j,2j+1), waves 4-7 -> window 1.
__global__ __launch_bounds__(512, 1)
void winattn_main(const float* __restrict__ x,
                  const _Float16* __restrict__ Wq, const _Float16* __restrict__ Wk,
                  const _Float16* __restrict__ Wv, const _Float16* __restrict__ Wo,
                  const f32x4* __restrict__ biasP, const float* __restrict__ bo,
                  float* __restrict__ out) {
    extern __shared__ __align__(16) char smem[];
    _Float16* sm_a  = reinterpret_cast<_Float16*>(smem);           // [128 tok][256 ch] 64 KB: xw, then o
    _Float16* sm_sc = reinterpret_cast<_Float16*>(smem + 65536);   // 8 x [64][64] f16 = 64 KB

    const int tid = threadIdx.x;
    const int lane = tid & 63;
    const int w = tid >> 6;          // 0..7
    const int j = w & 3;             // head-pair / ch-slice
    const int w1 = w >> 2;           // window within pair
    const int tb = w1 << 6;          // token base in xw
    const int g = lane >> 4;
    const int cl = lane & 15;
    const int bid = blockIdx.x;
    const int bb = bid >> 9, wy = (bid >> 4) & 31, wxp = bid & 15;
    const float* xb = x + (size_t)bb * 16777216u;      // 256*65536 floats per batch
    const int sp = wy * 2048 + wxp * 16;               // pair-row is 16 floats = one 64B line

    // ---- Stage 1: x (2-window pair) -> LDS xw [w1*64 + l][256 ch] f16, swizzled ----
    for (int i = 0; i < 16; ++i) {
        int qi = tid + (i << 9);                 // 8192 float4 chunks
        int c = qi >> 5;
        int rem = qi & 31;
        int iy = rem >> 2, ix4 = rem & 3;        // 4 float4s per 16-float pair-row
        f32x4 v4 = *reinterpret_cast<const f32x4*>(xb + (size_t)c * 65536 + sp + iy * 256 + ix4 * 4);
        int vw = ix4 >> 1, a = ix4 & 1;
        int l0 = (vw << 6) + (iy << 3) + (a << 2);
#pragma unroll
        for (int r = 0; r < 4; ++r) {
            int l = l0 + r;
            *reinterpret_cast<_Float16*>(reinterpret_cast<char*>(sm_a) + l * 512 +
                                         ((c << 1) ^ swzb(l))) = (_Float16)v4[r];
        }
    }
    __syncthreads();

    _Float16* scr = sm_sc + w * 4096;
    f16x8 qf[2][4], kf[2][4], vf[2][4];

    // ---- q^T, k^T, v -> register fragments (scr is wave-private; intra-wave LDS ordering) ----
    gemm_qk(Wq, sm_a, scr, j, tb, lane);
#pragma unroll
    for (int h = 0; h < 2; ++h)
#pragma unroll
        for (int lt = 0; lt < 4; ++lt) qf[h][lt] = ldsFrag128(scr, 16 * lt, 32 * h, lane);

    gemm_qk(Wk, sm_a, scr, j, tb, lane);
#pragma unroll
    for (int h = 0; h < 2; ++h)
#pragma unroll
        for (int mt = 0; mt < 4; ++mt) kf[h][mt] = ldsFrag128(scr, 16 * mt, 32 * h, lane);

    gemm_v(Wv, sm_a, scr, j, tb, lane);
#pragma unroll
    for (int h = 0; h < 2; ++h)
#pragma unroll
        for (int vt = 0; vt < 2; ++vt)
#pragma unroll
            for (int kb = 0; kb < 2; ++kb)
                vf[h][2 * vt + kb] = ldsFrag128(scr, 32 * h + 16 * vt, 32 * kb, lane);

    __syncthreads();   // all waves done with xw; sm_a becomes the o buffer (pair-row order)

    // ---- attention per head: S^T = K @ Q^T, softmax over m, o^T = V^T @ P^T ----
#pragma unroll
    for (int h = 0; h < 2; ++h) {
        int gh = 2 * j + h;
        f32x4 t[4][4];
#pragma unroll
        for (int mt = 0; mt < 4; ++mt)
#pragma unroll
            for (int lt = 0; lt < 4; ++lt) {
                f32x4 s = {0.f, 0.f, 0.f, 0.f};
                s = MFMA16(kf[h][mt], qf[h][lt], s);
                t[mt][lt] = s * 0.17677669529663687f + biasP[(gh * 16 + mt * 4 + lt) * 64 + lane];
            }
        // softmax over m for each column l (= lt, cl)
#pragma unroll
        for (int lt = 0; lt < 4; ++lt) {
            float mx = -1e30f;
#pragma unroll
            for (int mt = 0; mt < 4; ++mt)
#pragma unroll
                for (int r = 0; r < 4; ++r) mx = fmaxf(mx, t[mt][lt][r]);
            mx = fmaxf(mx, __shfl_xor(mx, 16));
            mx = fmaxf(mx, __shfl_xor(mx, 32));
            float sum = 0.f;
#pragma unroll
            for (int mt = 0; mt < 4; ++mt)
#pragma unroll
                for (int r = 0; r < 4; ++r) {
                    float e = exp2f((t[mt][lt][r] - mx) * 1.4426950408889634f);
                    t[mt][lt][r] = e;
                    sum += e;
                }
            sum += __shfl_xor(sum, 16);
            sum += __shfl_xor(sum, 32);
            float rs = 1.0f / sum;
#pragma unroll
            for (int mt = 0; mt < 4; ++mt)
#pragma unroll
                for (int r = 0; r < 4; ++r) t[mt][lt][r] *= rs;
        }
        // store P as row-major [l][m]
#pragma unroll
        for (int mt = 0; mt < 4; ++mt)
#pragma unroll
            for (int lt = 0; lt < 4; ++lt)
                stDT128(scr, 16 * lt + cl, 16 * mt + ((lane >> 4) << 2), t[mt][lt]);
        // PV: o^T = V^T @ P^T
        f32x4 oacc[2][4];
        {
            f32x4 z = {0.f, 0.f, 0.f, 0.f};
#pragma unroll
            for (int vt = 0; vt < 2; ++vt)
#pragma unroll
                for (int lt = 0; lt < 4; ++lt) oacc[vt][lt] = z;
        }
#pragma unroll
        for (int lt = 0; lt < 4; ++lt)
#pragma unroll
            for (int kb = 0; kb < 2; ++kb) {
                f16x8 pf = ldsFrag128(scr, 16 * lt, 32 * kb, lane);
#pragma unroll
                for (int vt = 0; vt < 2; ++vt)
                    oacc[vt][lt] = MFMA16(vf[h][2 * vt + kb], pf, oacc[vt][lt]);
            }
        // o -> sm_a in PAIR-ROW token order: row'' = (l>>3)*16 + w1*8 + (l&7)
#pragma unroll
        for (int vt = 0; vt < 2; ++vt)
#pragma unroll
            for (int lt = 0; lt < 4; ++lt) {
                int l = 16 * lt + cl;
                int rr = ((l >> 3) << 4) + (w1 << 3) + (l & 7);
                stDT512(sm_a, rr, 64 * j + 32 * h + 16 * vt + ((lane >> 4) << 2), oacc[vt][lt]);
            }
    }
    __syncthreads();

    // ---- output projection over the pair: out[tok''][oc] = o @ Wo^T + bo ----
    // wave handles oc slice [32w, 32w+32), all 128 pair tokens. Full 64B-line stores.
    {
        f32x4 z = {0.f, 0.f, 0.f, 0.f};
        f32x4 acc[8][2];
#pragma unroll
        for (int i = 0; i < 8; ++i)
#pragma unroll
            for (int jj = 0; jj < 2; ++jj) acc[i][jj] = z;
        for (int ks = 0; ks < 8; ++ks) {
            f16x8 B[2];
#pragma unroll
            for (int ct = 0; ct < 2; ++ct) B[ct] = gFrag(Wo, 32 * w + 16 * ct, 32 * ks, lane);
#pragma unroll
            for (int mt = 0; mt < 8; ++mt) {
                f16x8 A = ldsFrag512(sm_a, 16 * mt, 32 * ks, lane);
#pragma unroll
                for (int ct = 0; ct < 2; ++ct) acc[mt][ct] = MFMA16(A, B[ct], acc[mt][ct]);
            }
        }
#pragma unroll
        for (int ct = 0; ct < 2; ++ct) {
            int oc = 32 * w + 16 * ct + cl;
            float bov = bo[oc];
            size_t obase = ((size_t)(bb * 256 + oc)) * 65536u + sp;
#pragma unroll
            for (int mt = 0; mt < 8; ++mt) {   // mt = iy; lanes g=0..3 cover the full 64B line
                f32x4 vst = acc[mt][ct] + bov;
                *reinterpret_cast<f32x4*>(out + obase + mt * 256 + 4 * g) = vst;
            }
        }
    }
}

extern "C" void kernel_launch(void* const* d_in, const int* in_sizes, int n_in,
                              void* d_out, int out_size, void* d_ws, size_t ws_size,
                              hipStream_t stream) {
    (void)in_sizes; (void)n_in; (void)out_size; (void)ws_size;
    const float* x     = (const float*)d_in[0];
    const float* Wq    = (const float*)d_in[1];
    const float* Wk    = (const float*)d_in[2];
    const float* Wv    = (const float*)d_in[3];
    const float* table = (const float*)d_in[4];
    const float* Wo    = (const float*)d_in[5];
    const float* bo    = (const float*)d_in[6];
    const int*   rel   = (const int*)d_in[7];

    char* ws = (char*)d_ws;
    _Float16* wq = (_Float16*)(ws + 0);
    _Float16* wk = (_Float16*)(ws + 131072);
    _Float16* wv = (_Float16*)(ws + 262144);
    _Float16* wo = (_Float16*)(ws + 393216);
    f32x4*    bp = (f32x4*)(ws + 524288);     // 8192 float4 = 128 KB

    hipFuncSetAttribute(reinterpret_cast<const void*>(winattn_main),
                        hipFuncAttributeMaxDynamicSharedMemorySize, 131072);

    prep_kernel<<<256, 256, 0, stream>>>(Wq, Wk, Wv, Wo, table, rel, wq, wk, wv, wo, bp);
    winattn_main<<<2048, 512, 131072, stream>>>(x, wq, wk, wv, wo, bp, bo, (float*)d_out);
}